// Round 9
// baseline (368.634 us; speedup 1.0000x reference)
//
#include <hip/hip_runtime.h>

// B=8, C=64, H=256, W=256
#define BB 8
#define CC 64
#define HH 256
#define WW 256
#define HW (HH*WW)

typedef __attribute__((ext_vector_type(8))) short bf16x8;
typedef __attribute__((ext_vector_type(4))) float f32x4;
typedef __attribute__((ext_vector_type(2))) float f32x2;

__device__ __forceinline__ int reflect_idx(int v, int n) {
    // jnp.pad mode='reflect': -1 -> 1, n -> n-2
    if (v < 0) v = -v;
    if (v >= n) v = 2*n - 2 - v;
    return v;
}

// f32 -> bf16 (RNE) raw bits
__device__ __forceinline__ short f2bf(float f) {
    union { float f; unsigned u; } x; x.f = f;
    unsigned r = (x.u + 0x7fffu + ((x.u >> 16) & 1u)) >> 16;
    return (short)r;
}

__device__ __forceinline__ unsigned cvt_pk_bf16(float lo, float hi) {
    unsigned r;
    asm("v_cvt_pk_bf16_f32 %0, %1, %2" : "=v"(r) : "v"(lo), "v"(hi));
    return r;
}

// ---- prep kernel: reorder w_fuse into A-fragment-linear bf16 layout in d_ws ----
// afbuf[(g*4+mt)*64 + lane] = bf16x8 of w_fuse row (mt*16 + (lane&15)),
// k' = g*32 + (lane>>4)*8 + j ; src col = (i<16) ? g*16+i : 48+g*16+i
__global__ void corr_prep_kernel(const float* __restrict__ w_fuse,
                                 bf16x8* __restrict__ afbuf) {
    const int t = threadIdx.x;
    const int lane = t & 63;
    #pragma unroll
    for (int pass = 0; pass < 4; ++pass) {
        const int combo = (t >> 6) + pass * 4;      // 0..15 = g*4+mt
        const int g = combo >> 2, mt = combo & 3;
        const int m = mt * 16 + (lane & 15);
        const int kb = lane >> 4;
        bf16x8 v;
        #pragma unroll
        for (int j = 0; j < 8; ++j) {
            const int i = kb * 8 + j;
            const int src = (i < 16) ? (g * 16 + i) : (48 + g * 16 + i);
            v[j] = f2bf(w_fuse[m * 128 + src]);
        }
        afbuf[combo * 64 + lane] = v;
    }
}

__global__ __launch_bounds__(256, 5)
void corr_v9_kernel(const float* __restrict__ hs,
                    const float* __restrict__ refLR,
                    const float* __restrict__ w_first,
                    const float* __restrict__ b_first,
                    const bf16x8* __restrict__ afbuf,
                    const float* __restrict__ b_fuse,
                    float* __restrict__ out)
{
    // per-wave buffers only -> 27392 B total -> 5 blocks/CU
    __shared__ short s_fused[4][64 * 40];      // 20480 B [pix 64][k 32 pad 40]
    __shared__ float s_p01[4][216];            // p=hs*ref ch0,1 at 108 halo pos (6x18)
    __shared__ float s_p23[4][216];            // ch2,3

    const int t = threadIdx.x;
    const int wv = t >> 6, lane = t & 63;

    // XCD swizzle: each XCD owns one batch image
    const int d = (int)blockIdx.x;
    const int lid = (d & 7) * 256 + (d >> 3);
    const int bx = lid & 15, by = (lid >> 4) & 15, b = lid >> 8;

    // ---- wave strip: 4 rows x 16 cols within the 16x16 block tile ----
    const int y0 = by * 16 + wv * 4;
    const int x0 = bx * 16;

    // halo: 6 rows x 18 cols = 108 positions; lane owns pos=lane (+ 64+lane if lane<44)
    const bool has1 = lane < 44;
    int g0, g1;
    {
        const int py = lane / 18, px = lane % 18;
        g0 = reflect_idx(y0 + py - 1, HH) * WW + reflect_idx(x0 + px - 1, WW);
    }
    {
        const int pp = 64 + lane;
        const int py = pp / 18, px = pp % 18;
        const int gt = reflect_idx(y0 + py - 1, HH) * WW + reflect_idx(x0 + px - 1, WW);
        g1 = has1 ? gt : g0;
    }
    // lane's own pixel: row pyc (0..3), col pxc (0..15)
    const int pyc = lane >> 4, pxc = lane & 15;
    const int gc = (y0 + pyc) * WW + (x0 + pxc);

    // refLR halo values in registers (loaded once)
    const float* rb = refLR + (size_t)b * 9 * HW;
    float rin0[9], rin1[9];
    #pragma unroll
    for (int j = 0; j < 9; ++j) rin0[j] = rb[(size_t)j * HW + g0];
    #pragma unroll
    for (int j = 0; j < 9; ++j) rin1[j] = rb[(size_t)j * HW + g1];

    // accumulators (bias-initialized). C/D: col=lane&15 (pixel), row=(lane>>4)*4+r
    const int cl = lane & 15, kb = lane >> 4;
    f32x4 acc[4][4];
    #pragma unroll
    for (int mt = 0; mt < 4; ++mt) {
        #pragma unroll
        for (int r = 0; r < 4; ++r) {
            const float bv = b_fuse[mt * 16 + kb * 4 + r];
            #pragma unroll
            for (int nt = 0; nt < 4; ++nt) acc[mt][nt][r] = bv;
        }
    }

    const float* hsb = hs + (size_t)b * CC * HW;
    float* const sp01 = s_p01[wv];
    float* const sp23 = s_p23[wv];
    short* const sfw  = s_fused[wv];
    const int pb = (pyc * 18 + pxc) * 2;   // box-window base (float index, row stride 18)

    // prefetch chunk 0 hs values
    float h0[4], h1[4], hc[4];
    #pragma unroll
    for (int cc = 0; cc < 4; ++cc) {
        const float* hp = hsb + (size_t)cc * HW;
        h0[cc] = hp[g0]; h1[cc] = hp[g1]; hc[cc] = hp[gc];
    }

    #pragma unroll 1
    for (int ch = 0; ch < 16; ++ch) {
        const int c0 = ch * 4;

        // A-fragment prefetch for this group (issued a full chunk of work early;
        // coalesced b128, L2-resident)
        bf16x8 af[4];
        if ((ch & 3) == 3) {
            const int g = ch >> 2;
            #pragma unroll
            for (int mt = 0; mt < 4; ++mt)
                af[mt] = afbuf[(g * 4 + mt) * 64 + lane];
        }

        // ref 1x1 conv + leaky + p-products at owned halo positions
        float pr0[4], pr1[4], hcv[4];
        #pragma unroll
        for (int cc = 0; cc < 4; ++cc) {
            const int c = c0 + cc;
            float v0 = b_first[c], v1 = v0;
            #pragma unroll
            for (int j = 0; j < 9; ++j) {
                const float w = w_first[c * 9 + j];   // wave-uniform (s_load)
                v0 = fmaf(w, rin0[j], v0);
                v1 = fmaf(w, rin1[j], v1);
            }
            v0 = v0 > 0.f ? v0 : 0.1f * v0;
            v1 = v1 > 0.f ? v1 : 0.1f * v1;
            pr0[cc] = h0[cc] * v0;
            pr1[cc] = h1[cc] * v1;
            hcv[cc] = hc[cc];
        }
        *(f32x2*)&sp01[lane * 2] = (f32x2){pr0[0], pr0[1]};
        *(f32x2*)&sp23[lane * 2] = (f32x2){pr0[2], pr0[3]};
        if (has1) {
            *(f32x2*)&sp01[(64 + lane) * 2] = (f32x2){pr1[0], pr1[1]};
            *(f32x2*)&sp23[(64 + lane) * 2] = (f32x2){pr1[2], pr1[3]};
        }
        // wave-local LDS RAW fence (data is wave-private; no s_barrier)
        asm volatile("s_waitcnt lgkmcnt(0)" ::: "memory");

        // 3x3 box-sum of p (row stride 18 -> flat bank profile)
        f32x2 a01 = (f32x2){0.f, 0.f}, a23 = (f32x2){0.f, 0.f};
        #pragma unroll
        for (int dy = 0; dy < 3; ++dy)
            #pragma unroll
            for (int dx = 0; dx < 3; ++dx) {
                const int o = pb + (dy * 18 + dx) * 2;
                a01 += *(const f32x2*)&sp01[o];
                a23 += *(const f32x2*)&sp23[o];
            }

        // issue next chunk's hs loads (hidden under sigmoid/MFMA/next conv)
        {
            const int cn = ((ch + 1) & 15) * 4;
            #pragma unroll
            for (int cc = 0; cc < 4; ++cc) {
                const float* hp = hsb + (size_t)(cn + cc) * HW;
                h0[cc] = hp[g0]; h1[cc] = hp[g1]; hc[cc] = hp[gc];
            }
        }

        // sigmoid gate, bf16 pack, write k-slice of fused
        const float cr[4] = {a01[0], a01[1], a23[0], a23[1]};
        float av[4];
        #pragma unroll
        for (int cc = 0; cc < 4; ++cc)
            av[cc] = __builtin_amdgcn_rcpf(
                1.0f + __builtin_amdgcn_exp2f(cr[cc] * -1.44269504088896f)) * hcv[cc];
        uint2 ua, uh;
        ua.x = cvt_pk_bf16(av[0], av[1]);
        ua.y = cvt_pk_bf16(av[2], av[3]);
        uh.x = cvt_pk_bf16(hcv[0], hcv[1]);
        uh.y = cvt_pk_bf16(hcv[2], hcv[3]);
        const int k4 = (ch & 3) * 4;
        *(uint2*)&sfw[lane * 40 + k4]      = ua;   // att*hs at k = k4..k4+3
        *(uint2*)&sfw[lane * 40 + 16 + k4] = uh;   // hs     at k = 16+k4..

        // group boundary: one k=32 MFMA slice, accumulate
        if ((ch & 3) == 3) {
            asm volatile("s_waitcnt lgkmcnt(0)" ::: "memory");
            #pragma unroll
            for (int nt = 0; nt < 4; ++nt) {
                const bf16x8 bf = *(const bf16x8*)&sfw[(nt * 16 + cl) * 40 + kb * 8];
                #pragma unroll
                for (int mt = 0; mt < 4; ++mt)
                    acc[mt][nt] = __builtin_amdgcn_mfma_f32_16x16x32_bf16(af[mt], bf, acc[mt][nt], 0, 0, 0);
            }
        }
    }

    // ---- epilogue: every store instruction = 4 channel-planes x full 64B lines ----
    float* const ob = out + (size_t)b * CC * HW;
    #pragma unroll
    for (int mt = 0; mt < 4; ++mt) {
        #pragma unroll
        for (int nt = 0; nt < 4; ++nt) {
            #pragma unroll
            for (int r = 0; r < 4; ++r) {
                const int o = mt * 16 + kb * 4 + r;
                ob[(size_t)o * HW + (size_t)(y0 + nt) * WW + (x0 + cl)] = acc[mt][nt][r];
            }
        }
    }
}

extern "C" void kernel_launch(void* const* d_in, const int* in_sizes, int n_in,
                              void* d_out, int out_size, void* d_ws, size_t ws_size,
                              hipStream_t stream) {
    const float* hs      = (const float*)d_in[0];
    const float* refLR   = (const float*)d_in[1];
    const float* w_first = (const float*)d_in[2];
    const float* b_first = (const float*)d_in[3];
    const float* w_fuse  = (const float*)d_in[4];
    const float* b_fuse  = (const float*)d_in[5];
    float* out = (float*)d_out;
    bf16x8* afbuf = (bf16x8*)d_ws;    // 16 combos * 64 lanes * 16B = 65536 B

    corr_prep_kernel<<<dim3(1), dim3(256), 0, stream>>>(w_fuse, afbuf);
    corr_v9_kernel<<<dim3(2048), dim3(256), 0, stream>>>(hs, refLR, w_first, b_first,
                                                         afbuf, b_fuse, out);
}

// Round 10
// 116.480 us; speedup vs baseline: 3.1648x; 3.1648x over previous
//
#include <hip/hip_runtime.h>

// B=8, C=64, H=256, W=256
#define BB 8
#define CC 64
#define HH 256
#define WW 256
#define HW (HH*WW)

typedef __attribute__((ext_vector_type(8))) short bf16x8;
typedef __attribute__((ext_vector_type(4))) float f32x4;
typedef __attribute__((ext_vector_type(2))) float f32x2;

__device__ __forceinline__ int reflect_idx(int v, int n) {
    // jnp.pad mode='reflect': -1 -> 1, n -> n-2
    if (v < 0) v = -v;
    if (v >= n) v = 2*n - 2 - v;
    return v;
}

// f32 -> bf16 (RNE) raw bits
__device__ __forceinline__ short f2bf(float f) {
    union { float f; unsigned u; } x; x.f = f;
    unsigned r = (x.u + 0x7fffu + ((x.u >> 16) & 1u)) >> 16;
    return (short)r;
}

__device__ __forceinline__ unsigned cvt_pk_bf16(float lo, float hi) {
    unsigned r;
    asm("v_cvt_pk_bf16_f32 %0, %1, %2" : "=v"(r) : "v"(lo), "v"(hi));
    return r;
}

// ---- prep kernel: reorder w_fuse into A-fragment-linear bf16 layout in d_ws ----
// afbuf[(g*4+mt)*64 + lane] = bf16x8 of w_fuse row (mt*16 + (lane&15)),
// k' = g*32 + (lane>>4)*8 + j ; src col = (i<16) ? g*16+i : 48+g*16+i
__global__ void corr_prep_kernel(const float* __restrict__ w_fuse,
                                 bf16x8* __restrict__ afbuf) {
    const int t = threadIdx.x;
    const int lane = t & 63;
    #pragma unroll
    for (int pass = 0; pass < 4; ++pass) {
        const int combo = (t >> 6) + pass * 4;      // 0..15 = g*4+mt
        const int g = combo >> 2, mt = combo & 3;
        const int m = mt * 16 + (lane & 15);
        const int kb = lane >> 4;
        bf16x8 v;
        #pragma unroll
        for (int j = 0; j < 8; ++j) {
            const int i = kb * 8 + j;
            const int src = (i < 16) ? (g * 16 + i) : (48 + g * 16 + i);
            v[j] = f2bf(w_fuse[m * 128 + src]);
        }
        afbuf[combo * 64 + lane] = v;
    }
}

// launch_bounds(…,3): R9's (…,5) forced a ~102-VGPR cap -> acc spilled to scratch
// (~570MB of HBM spill traffic, 368us). Bound 3 keeps the allocator comfortable;
// occupancy comes from the LDS cut (27.6KB -> up to 5 blocks/CU) instead.
__global__ __launch_bounds__(256, 3)
void corr_v10_kernel(const float* __restrict__ hs,
                     const float* __restrict__ refLR,
                     const float* __restrict__ w_first,
                     const float* __restrict__ b_first,
                     const bf16x8* __restrict__ afbuf,
                     const float* __restrict__ b_fuse,
                     float* __restrict__ out)
{
    // per-wave buffers only -> 27392 B total
    __shared__ short s_fused[4][64 * 40];      // 20480 B [pix 64][k 32 pad 40]
    __shared__ float s_p01[4][216];            // p=hs*ref ch0,1 at 108 halo pos (6x18)
    __shared__ float s_p23[4][216];            // ch2,3

    const int t = threadIdx.x;
    const int wv = t >> 6, lane = t & 63;

    // XCD swizzle: each XCD owns one batch image
    const int d = (int)blockIdx.x;
    const int lid = (d & 7) * 256 + (d >> 3);
    const int bx = lid & 15, by = (lid >> 4) & 15, b = lid >> 8;

    // ---- wave strip: 4 rows x 16 cols within the 16x16 block tile ----
    const int y0 = by * 16 + wv * 4;
    const int x0 = bx * 16;

    // halo: 6 rows x 18 cols = 108 positions; lane owns pos=lane (+ 64+lane if lane<44)
    const bool has1 = lane < 44;
    int g0, g1;
    {
        const int py = lane / 18, px = lane % 18;
        g0 = reflect_idx(y0 + py - 1, HH) * WW + reflect_idx(x0 + px - 1, WW);
    }
    {
        const int pp = 64 + lane;
        const int py = pp / 18, px = pp % 18;
        const int gt = reflect_idx(y0 + py - 1, HH) * WW + reflect_idx(x0 + px - 1, WW);
        g1 = has1 ? gt : g0;
    }
    // lane's own pixel: row pyc (0..3), col pxc (0..15)
    const int pyc = lane >> 4, pxc = lane & 15;
    const int gc = (y0 + pyc) * WW + (x0 + pxc);

    // refLR halo values in registers (loaded once)
    const float* rb = refLR + (size_t)b * 9 * HW;
    float rin0[9], rin1[9];
    #pragma unroll
    for (int j = 0; j < 9; ++j) rin0[j] = rb[(size_t)j * HW + g0];
    #pragma unroll
    for (int j = 0; j < 9; ++j) rin1[j] = rb[(size_t)j * HW + g1];

    // accumulators (bias-initialized). C/D: col=lane&15 (pixel), row=(lane>>4)*4+r
    const int cl = lane & 15, kb = lane >> 4;
    f32x4 acc[4][4];
    #pragma unroll
    for (int mt = 0; mt < 4; ++mt) {
        #pragma unroll
        for (int r = 0; r < 4; ++r) {
            const float bv = b_fuse[mt * 16 + kb * 4 + r];
            #pragma unroll
            for (int nt = 0; nt < 4; ++nt) acc[mt][nt][r] = bv;
        }
    }

    const float* hsb = hs + (size_t)b * CC * HW;
    float* const sp01 = s_p01[wv];
    float* const sp23 = s_p23[wv];
    short* const sfw  = s_fused[wv];
    const int pb = (pyc * 18 + pxc) * 2;   // box-window base (float index, row stride 18)

    // prefetch chunk 0 hs values
    float h0[4], h1[4], hc[4];
    #pragma unroll
    for (int cc = 0; cc < 4; ++cc) {
        const float* hp = hsb + (size_t)cc * HW;
        h0[cc] = hp[g0]; h1[cc] = hp[g1]; hc[cc] = hp[gc];
    }

    #pragma unroll 1
    for (int ch = 0; ch < 16; ++ch) {
        const int c0 = ch * 4;

        // A-fragment prefetch for this group (issued a conv-phase early; L2-resident)
        bf16x8 af[4];
        if ((ch & 3) == 3) {
            const int g = ch >> 2;
            #pragma unroll
            for (int mt = 0; mt < 4; ++mt)
                af[mt] = afbuf[(g * 4 + mt) * 64 + lane];
        }

        // ref 1x1 conv + leaky + p-products at owned halo positions
        float pr0[4], pr1[4], hcv[4];
        #pragma unroll
        for (int cc = 0; cc < 4; ++cc) {
            const int c = c0 + cc;
            float v0 = b_first[c], v1 = v0;
            #pragma unroll
            for (int j = 0; j < 9; ++j) {
                const float w = w_first[c * 9 + j];   // wave-uniform (s_load)
                v0 = fmaf(w, rin0[j], v0);
                v1 = fmaf(w, rin1[j], v1);
            }
            v0 = v0 > 0.f ? v0 : 0.1f * v0;
            v1 = v1 > 0.f ? v1 : 0.1f * v1;
            pr0[cc] = h0[cc] * v0;
            pr1[cc] = h1[cc] * v1;
            hcv[cc] = hc[cc];
        }
        *(f32x2*)&sp01[lane * 2] = (f32x2){pr0[0], pr0[1]};
        *(f32x2*)&sp23[lane * 2] = (f32x2){pr0[2], pr0[3]};
        if (has1) {
            *(f32x2*)&sp01[(64 + lane) * 2] = (f32x2){pr1[0], pr1[1]};
            *(f32x2*)&sp23[(64 + lane) * 2] = (f32x2){pr1[2], pr1[3]};
        }
        // wave-local LDS RAW fence (data is wave-private; no s_barrier)
        asm volatile("s_waitcnt lgkmcnt(0)" ::: "memory");

        // 3x3 box-sum of p (row stride 18 -> flat bank profile)
        f32x2 a01 = (f32x2){0.f, 0.f}, a23 = (f32x2){0.f, 0.f};
        #pragma unroll
        for (int dy = 0; dy < 3; ++dy)
            #pragma unroll
            for (int dx = 0; dx < 3; ++dx) {
                const int o = pb + (dy * 18 + dx) * 2;
                a01 += *(const f32x2*)&sp01[o];
                a23 += *(const f32x2*)&sp23[o];
            }

        // issue next chunk's hs loads (hidden under sigmoid/MFMA/next conv)
        {
            const int cn = ((ch + 1) & 15) * 4;
            #pragma unroll
            for (int cc = 0; cc < 4; ++cc) {
                const float* hp = hsb + (size_t)(cn + cc) * HW;
                h0[cc] = hp[g0]; h1[cc] = hp[g1]; hc[cc] = hp[gc];
            }
        }

        // sigmoid gate, bf16 pack, write k-slice of fused
        const float cr[4] = {a01[0], a01[1], a23[0], a23[1]};
        float av[4];
        #pragma unroll
        for (int cc = 0; cc < 4; ++cc)
            av[cc] = __builtin_amdgcn_rcpf(
                1.0f + __builtin_amdgcn_exp2f(cr[cc] * -1.44269504088896f)) * hcv[cc];
        uint2 ua, uh;
        ua.x = cvt_pk_bf16(av[0], av[1]);
        ua.y = cvt_pk_bf16(av[2], av[3]);
        uh.x = cvt_pk_bf16(hcv[0], hcv[1]);
        uh.y = cvt_pk_bf16(hcv[2], hcv[3]);
        const int k4 = (ch & 3) * 4;
        *(uint2*)&sfw[lane * 40 + k4]      = ua;   // att*hs at k = k4..k4+3
        *(uint2*)&sfw[lane * 40 + 16 + k4] = uh;   // hs     at k = 16+k4..

        // group boundary: one k=32 MFMA slice, accumulate
        if ((ch & 3) == 3) {
            asm volatile("s_waitcnt lgkmcnt(0)" ::: "memory");
            #pragma unroll
            for (int nt = 0; nt < 4; ++nt) {
                const bf16x8 bf = *(const bf16x8*)&sfw[(nt * 16 + cl) * 40 + kb * 8];
                #pragma unroll
                for (int mt = 0; mt < 4; ++mt)
                    acc[mt][nt] = __builtin_amdgcn_mfma_f32_16x16x32_bf16(af[mt], bf, acc[mt][nt], 0, 0, 0);
            }
        }
    }

    // ---- epilogue: every store instruction = 4 channel-planes x full 64B lines ----
    float* const ob = out + (size_t)b * CC * HW;
    #pragma unroll
    for (int mt = 0; mt < 4; ++mt) {
        #pragma unroll
        for (int nt = 0; nt < 4; ++nt) {
            #pragma unroll
            for (int r = 0; r < 4; ++r) {
                const int o = mt * 16 + kb * 4 + r;
                ob[(size_t)o * HW + (size_t)(y0 + nt) * WW + (x0 + cl)] = acc[mt][nt][r];
            }
        }
    }
}

extern "C" void kernel_launch(void* const* d_in, const int* in_sizes, int n_in,
                              void* d_out, int out_size, void* d_ws, size_t ws_size,
                              hipStream_t stream) {
    const float* hs      = (const float*)d_in[0];
    const float* refLR   = (const float*)d_in[1];
    const float* w_first = (const float*)d_in[2];
    const float* b_first = (const float*)d_in[3];
    const float* w_fuse  = (const float*)d_in[4];
    const float* b_fuse  = (const float*)d_in[5];
    float* out = (float*)d_out;
    bf16x8* afbuf = (bf16x8*)d_ws;    // 16 combos * 64 lanes * 16B = 65536 B

    corr_prep_kernel<<<dim3(1), dim3(256), 0, stream>>>(w_fuse, afbuf);
    corr_v10_kernel<<<dim3(2048), dim3(256), 0, stream>>>(hs, refLR, w_first, b_first,
                                                          afbuf, b_fuse, out);
}